// Round 1
// baseline (379.076 us; speedup 1.0000x reference)
//
#include <hip/hip_runtime.h>
#include <hip/hip_bf16.h>

typedef __attribute__((ext_vector_type(8))) short short8;
typedef __attribute__((ext_vector_type(4))) float f32x4;
typedef unsigned short u16;
typedef unsigned int u32;

#define NROWS 16384
#define KDIM 16384
#define EPS 1e-6f

__device__ __forceinline__ u16 f2bf(float x) {
    union { float f; u32 u; } v; v.f = x;
    u32 u = v.u;
    u32 r = (u + 0x7FFFu + ((u >> 16) & 1u)) >> 16;  // RNE
    return (u16)r;
}

// ---------------- Stage 0: transpose weight -> Wt[64][256] ----------------
__global__ __launch_bounds__(256) void wt_kernel(const float* __restrict__ W,
                                                 float* __restrict__ Wt) {
    int idx = blockIdx.x * 256 + threadIdx.x;  // 16384
    int k = idx >> 6, c = idx & 63;
    Wt[c * 256 + k] = W[idx];
}

// ---------------- Stage 1: support = input @ W (fp32, exact-ish) ----------
__global__ __launch_bounds__(256) void support_kernel(
    const float* __restrict__ inp, const float* __restrict__ Wt,
    float* __restrict__ sup)
{
    int tid = threadIdx.x;
    int col = tid & 63;
    int rr = tid >> 6;                        // 0..3
    int rowbase = blockIdx.x * 32 + rr * 8;   // 8 rows per thread
    const float4* wt4 = (const float4*)(Wt + (size_t)col * 256);
    float acc[8];
#pragma unroll
    for (int i = 0; i < 8; ++i) acc[i] = 0.f;
    for (int k4 = 0; k4 < 64; ++k4) {
        float4 wv = wt4[k4];
#pragma unroll
        for (int i = 0; i < 8; ++i) {
            float4 iv = *((const float4*)(inp + (size_t)(rowbase + i) * 256) + k4);
            acc[i] += iv.x * wv.x + iv.y * wv.y + iv.z * wv.z + iv.w * wv.w;
        }
    }
#pragma unroll
    for (int i = 0; i < 8; ++i)
        sup[(size_t)(rowbase + i) * 64 + col] = acc[i];
}

// ---------------- Stage 2: global min (two-kernel, deterministic) ---------
__global__ __launch_bounds__(256) void min_part_kernel(
    const float* __restrict__ sup, float* __restrict__ partmin)
{
    __shared__ float wmin[4];
    int tid = threadIdx.x;
    const float4* s4 = (const float4*)sup;   // 262144 float4 total
    size_t idx = (size_t)blockIdx.x * 256 + tid;
    float m = 3.4e38f;
#pragma unroll
    for (int j = 0; j < 4; ++j) {
        float4 v = s4[idx + (size_t)j * 65536];
        m = fminf(m, fminf(fminf(v.x, v.y), fminf(v.z, v.w)));
    }
#pragma unroll
    for (int off = 32; off; off >>= 1) m = fminf(m, __shfl_down(m, off, 64));
    if ((tid & 63) == 0) wmin[tid >> 6] = m;
    __syncthreads();
    if (tid == 0)
        partmin[blockIdx.x] = fminf(fminf(wmin[0], wmin[1]), fminf(wmin[2], wmin[3]));
}

__global__ __launch_bounds__(256) void min_final_kernel(
    const float* __restrict__ partmin, float* __restrict__ mu)
{
    __shared__ float wmin[4];
    int tid = threadIdx.x;
    float m = partmin[tid];
#pragma unroll
    for (int off = 32; off; off >>= 1) m = fminf(m, __shfl_down(m, off, 64));
    if ((tid & 63) == 0) wmin[tid >> 6] = m;
    __syncthreads();
    if (tid == 0)
        mu[0] = fminf(fminf(wmin[0], wmin[1]), fminf(wmin[2], wmin[3]));
}

// ---------------- Stage 3: Bt[n][k] bf16; n<64: s^(p+1), n>=64: s^p -------
__global__ __launch_bounds__(256) void build_bt_kernel(
    const float* __restrict__ sup, const float* __restrict__ muptr,
    const int* __restrict__ pptr, u16* __restrict__ Bt)
{
    int k = blockIdx.x * 256 + threadIdx.x;   // 0..16383
    float mu = *muptr;
    int p = *pptr;
    const float4* srow = (const float4*)(sup + (size_t)k * 64);
#pragma unroll
    for (int j = 0; j < 16; ++j) {
        float4 v = srow[j];
        float ss[4] = {v.x, v.y, v.z, v.w};
#pragma unroll
        for (int q = 0; q < 4; ++q) {
            int c = j * 4 + q;
            float s = ss[q] - mu + EPS;
            float d = 1.f;
            for (int i = 0; i < p; ++i) d *= s;   // s^p
            Bt[(size_t)c * KDIM + k] = f2bf(d * s);          // top
            Bt[(size_t)(c + 64) * KDIM + k] = f2bf(d);       // down
        }
    }
}

// ---------------- Stage 4: fused GEMM  C = adj @ [top|down], ratio+mu+bias -
// BM=32, BN=128, BK=64, 4 waves, dbuf LDS, XOR-swizzled 16B granules.
__global__ __launch_bounds__(256, 2) void gemm_kernel(
    const float* __restrict__ adj, const u16* __restrict__ Bt,
    const float* __restrict__ bias, const float* __restrict__ muptr,
    float* __restrict__ out)
{
    __shared__ __align__(16) u16 Ash[2][32 * 64];    //  4 KB x2
    __shared__ __align__(16) u16 Bsh[2][128 * 64];   // 16 KB x2

    const int tid = threadIdx.x;
    const int rowbase = blockIdx.x * 32;

    // --- staging indices ---
    const int am = tid >> 3;            // 0..31  (A row)
    const int ac = tid & 7;             // 0..7   (A 16B-granule = 8 f32)
    const int bn = tid >> 1;            // 0..127 (B row = col n)
    const int bh = tid & 1;             // which 32-k half
    const float* aptr = adj + (size_t)(rowbase + am) * KDIM + ac * 8;
    const u16*   bptr = Bt + (size_t)bn * KDIM + bh * 32;
    const int aw_idx  = am * 8 + (ac ^ (am & 7));
    const int bs_base = bn * 8;
    const int bsw     = bn & 7;

    // --- compute indices ---
    const int lane = tid & 63;
    const int w    = tid >> 6;          // wave 0..3
    const int l15  = lane & 15;
    const int lg   = lane >> 4;
    const int arow0 = l15 * 8,        arow1 = (16 + l15) * 8;
    const int asw   = l15 & 7;
    const int n0    = w * 16 + l15;     // output col (0..63)
    const int brow0 = n0 * 8,         brow1 = (n0 + 64) * 8;
    const int bsw2  = n0 & 7;

    f32x4 acc00 = {0.f, 0.f, 0.f, 0.f};
    f32x4 acc01 = acc00, acc10 = acc00, acc11 = acc00;

    float4 ra0, ra1;
    uint4 rb0, rb1, rb2, rb3;

    const int NT = KDIM / 64;   // 256 K-tiles

    // prologue: load tile 0
    {
        const float4* ap = (const float4*)aptr;
        ra0 = ap[0]; ra1 = ap[1];
        const uint4* bp = (const uint4*)bptr;
        rb0 = bp[0]; rb1 = bp[1]; rb2 = bp[2]; rb3 = bp[3];
    }

    for (int t = 0; t < NT; ++t) {
        const int buf = t & 1;
        // stage regs -> LDS (compiler inserts vmcnt wait)
        {
            uint4 awv;
            awv.x = (u32)f2bf(ra0.x) | ((u32)f2bf(ra0.y) << 16);
            awv.y = (u32)f2bf(ra0.z) | ((u32)f2bf(ra0.w) << 16);
            awv.z = (u32)f2bf(ra1.x) | ((u32)f2bf(ra1.y) << 16);
            awv.w = (u32)f2bf(ra1.z) | ((u32)f2bf(ra1.w) << 16);
            ((uint4*)Ash[buf])[aw_idx] = awv;
            uint4* bs = (uint4*)Bsh[buf];
            bs[bs_base + ((bh * 4 + 0) ^ bsw)] = rb0;
            bs[bs_base + ((bh * 4 + 1) ^ bsw)] = rb1;
            bs[bs_base + ((bh * 4 + 2) ^ bsw)] = rb2;
            bs[bs_base + ((bh * 4 + 3) ^ bsw)] = rb3;
        }
        __syncthreads();
        // issue next-tile loads; they stay in flight under the MFMAs
        if (t + 1 < NT) {
            const float4* ap = (const float4*)(aptr + (size_t)(t + 1) * 64);
            ra0 = ap[0]; ra1 = ap[1];
            const uint4* bp = (const uint4*)(bptr + (size_t)(t + 1) * 64);
            rb0 = bp[0]; rb1 = bp[1]; rb2 = bp[2]; rb3 = bp[3];
        }
        // compute current tile
        {
            const short8* As = (const short8*)Ash[buf];
            const short8* Bs = (const short8*)Bsh[buf];
#pragma unroll
            for (int ks = 0; ks < 2; ++ks) {
                const int g = ks * 4 + lg;
                short8 a0 = As[arow0 + (g ^ asw)];
                short8 a1 = As[arow1 + (g ^ asw)];
                short8 b0 = Bs[brow0 + (g ^ bsw2)];
                short8 b1 = Bs[brow1 + (g ^ bsw2)];
                acc00 = __builtin_amdgcn_mfma_f32_16x16x32_bf16(a0, b0, acc00, 0, 0, 0);
                acc01 = __builtin_amdgcn_mfma_f32_16x16x32_bf16(a0, b1, acc01, 0, 0, 0);
                acc10 = __builtin_amdgcn_mfma_f32_16x16x32_bf16(a1, b0, acc10, 0, 0, 0);
                acc11 = __builtin_amdgcn_mfma_f32_16x16x32_bf16(a1, b1, acc11, 0, 0, 0);
            }
        }
        // single barrier/iter is sufficient with double buffering:
        // a wave can only be 1 iteration ahead, and it writes the other buffer.
    }

    // epilogue: ratio + mu + bias.  C layout: col=lane&15, row=(lane>>4)*4+r
    const float mu = *muptr;
    const float bv = bias[n0];
#pragma unroll
    for (int r = 0; r < 4; ++r) {
        int row0 = rowbase + lg * 4 + r;
        int row1 = row0 + 16;
        out[(size_t)row0 * 64 + n0] = acc00[r] / acc01[r] + mu + bv;
        out[(size_t)row1 * 64 + n0] = acc10[r] / acc11[r] + mu + bv;
    }
}

extern "C" void kernel_launch(void* const* d_in, const int* in_sizes, int n_in,
                              void* d_out, int out_size, void* d_ws, size_t ws_size,
                              hipStream_t stream)
{
    const float* inp  = (const float*)d_in[0];
    const float* adj  = (const float*)d_in[1];
    const float* W    = (const float*)d_in[2];
    const float* bias = (const float*)d_in[3];
    const int*   p    = (const int*)d_in[4];
    float* out = (float*)d_out;

    // workspace layout: Bt (4 MB) | partmin (1 KB) | mu | Wt (64 KB)
    char* ws = (char*)d_ws;
    u16*   Bt      = (u16*)ws;
    float* partmin = (float*)(ws + (size_t)4 * 1024 * 1024);
    float* mu      = partmin + 256;
    float* Wt      = (float*)(ws + (size_t)4 * 1024 * 1024 + 4096);

    float* sup = out;   // park support in d_out; GEMM overwrites it last

    wt_kernel      <<<64,  256, 0, stream>>>(W, Wt);
    support_kernel <<<512, 256, 0, stream>>>(inp, Wt, sup);
    min_part_kernel<<<256, 256, 0, stream>>>(sup, partmin);
    min_final_kernel<<<1,  256, 0, stream>>>(partmin, mu);
    build_bt_kernel<<<64,  256, 0, stream>>>(sup, mu, p, Bt);
    gemm_kernel    <<<512, 256, 0, stream>>>(adj, Bt, bias, mu, out);
}

// Round 2
// 290.889 us; speedup vs baseline: 1.3032x; 1.3032x over previous
//
#include <hip/hip_runtime.h>
#include <hip/hip_bf16.h>

typedef __attribute__((ext_vector_type(8))) short short8;
typedef __attribute__((ext_vector_type(4))) float f32x4;
typedef unsigned short u16;
typedef unsigned int u32;

#define NROWS 16384
#define KDIM 16384
#define EPS 1e-6f

__device__ __forceinline__ u16 f2bf(float x) {
    union { float f; u32 u; } v; v.f = x;
    u32 u = v.u;
    u32 r = (u + 0x7FFFu + ((u >> 16) & 1u)) >> 16;  // RNE
    return (u16)r;
}

__device__ __forceinline__ void glds16(const void* g, void* l) {
    __builtin_amdgcn_global_load_lds(
        (const __attribute__((address_space(1))) void*)g,
        (__attribute__((address_space(3))) void*)l, 16, 0, 0);
}

__device__ __forceinline__ short cvbf(float x) {
    __hip_bfloat16 h = __float2bfloat16(x);
    return *(short*)&h;
}

__device__ __forceinline__ short8 cvt8(float4 a, float4 b) {
    short8 r = { cvbf(a.x), cvbf(a.y), cvbf(a.z), cvbf(a.w),
                 cvbf(b.x), cvbf(b.y), cvbf(b.z), cvbf(b.w) };
    return r;
}

// ---------------- Stage 0: transpose weight -> Wt[64][256] ----------------
__global__ __launch_bounds__(256) void wt_kernel(const float* __restrict__ W,
                                                 float* __restrict__ Wt) {
    int idx = blockIdx.x * 256 + threadIdx.x;  // 16384
    int k = idx >> 6, c = idx & 63;
    Wt[c * 256 + k] = W[idx];
}

// ---------------- Stage 1: support = input @ W (fp32) ---------------------
__global__ __launch_bounds__(256) void support_kernel(
    const float* __restrict__ inp, const float* __restrict__ Wt,
    float* __restrict__ sup)
{
    int tid = threadIdx.x;
    int col = tid & 63;
    int rr = tid >> 6;                        // 0..3
    int rowbase = blockIdx.x * 32 + rr * 8;   // 8 rows per thread
    const float4* wt4 = (const float4*)(Wt + (size_t)col * 256);
    float acc[8];
#pragma unroll
    for (int i = 0; i < 8; ++i) acc[i] = 0.f;
    for (int k4 = 0; k4 < 64; ++k4) {
        float4 wv = wt4[k4];
#pragma unroll
        for (int i = 0; i < 8; ++i) {
            float4 iv = *((const float4*)(inp + (size_t)(rowbase + i) * 256) + k4);
            acc[i] += iv.x * wv.x + iv.y * wv.y + iv.z * wv.z + iv.w * wv.w;
        }
    }
#pragma unroll
    for (int i = 0; i < 8; ++i)
        sup[(size_t)(rowbase + i) * 64 + col] = acc[i];
}

// ---------------- Stage 2: global min ------------------------------------
__global__ __launch_bounds__(256) void min_part_kernel(
    const float* __restrict__ sup, float* __restrict__ partmin)
{
    __shared__ float wmin[4];
    int tid = threadIdx.x;
    const float4* s4 = (const float4*)sup;
    size_t idx = (size_t)blockIdx.x * 256 + tid;
    float m = 3.4e38f;
#pragma unroll
    for (int j = 0; j < 4; ++j) {
        float4 v = s4[idx + (size_t)j * 65536];
        m = fminf(m, fminf(fminf(v.x, v.y), fminf(v.z, v.w)));
    }
#pragma unroll
    for (int off = 32; off; off >>= 1) m = fminf(m, __shfl_down(m, off, 64));
    if ((tid & 63) == 0) wmin[tid >> 6] = m;
    __syncthreads();
    if (tid == 0)
        partmin[blockIdx.x] = fminf(fminf(wmin[0], wmin[1]), fminf(wmin[2], wmin[3]));
}

__global__ __launch_bounds__(256) void min_final_kernel(
    const float* __restrict__ partmin, float* __restrict__ mu)
{
    __shared__ float wmin[4];
    int tid = threadIdx.x;
    float m = partmin[tid];
#pragma unroll
    for (int off = 32; off; off >>= 1) m = fminf(m, __shfl_down(m, off, 64));
    if ((tid & 63) == 0) wmin[tid >> 6] = m;
    __syncthreads();
    if (tid == 0)
        mu[0] = fminf(fminf(wmin[0], wmin[1]), fminf(wmin[2], wmin[3]));
}

// ---------------- Stage 3: Bt[n][k] bf16; n<64: s^(p+1), n>=64: s^p -------
__global__ __launch_bounds__(256) void build_bt_kernel(
    const float* __restrict__ sup, const float* __restrict__ muptr,
    const int* __restrict__ pptr, u16* __restrict__ Bt)
{
    int k = blockIdx.x * 256 + threadIdx.x;   // 0..16383
    float mu = *muptr;
    int p = *pptr;
    const float4* srow = (const float4*)(sup + (size_t)k * 64);
#pragma unroll
    for (int j = 0; j < 16; ++j) {
        float4 v = srow[j];
        float ss[4] = {v.x, v.y, v.z, v.w};
#pragma unroll
        for (int q = 0; q < 4; ++q) {
            int c = j * 4 + q;
            float s = ss[q] - mu + EPS;
            float d = 1.f;
            for (int i = 0; i < p; ++i) d *= s;   // s^p
            Bt[(size_t)c * KDIM + k] = f2bf(d * s);          // top
            Bt[(size_t)(c + 64) * KDIM + k] = f2bf(d);       // down
        }
    }
}

// ---------------- Stage 4: GEMM partials, K-split=2 -----------------------
// BM=64, BN=128 (64 top | 64 down), BK=64, 512 thr (8 waves), grid=512.
// A staged f32 via global_load_lds (convert after ds_read); B staged bf16.
// XOR swizzle: LDS[r][x] holds global granule (x ^ (r&7)) -> conflict-free
// ds_read_b128 columns; glds dest stays linear (rule: swizzle the SOURCE).
#define BM 64
#define BN 128
#define BK 64
#define KH 8192
#define NTI 128   // KH/BK

__global__ __launch_bounds__(512, 4) void gemm_kernel(
    const float* __restrict__ adj, const u16* __restrict__ Bt,
    float* __restrict__ Pp)
{
    __shared__ __align__(16) float Ash[2][BM * BK];   // 16 KB x2 (f32)
    __shared__ __align__(16) u16  Bsh[2][BN * BK];    // 16 KB x2 (bf16)

    const int tid = threadIdx.x;
    const int rb = blockIdx.x >> 1;
    const int h  = blockIdx.x & 1;
    const size_t rowbase = (size_t)rb * BM;
    const size_t kbase = (size_t)h * KH;

    // --- staging: thread handles granules g = tid and tid+512 (16 B each)
    const int ga0 = tid,        ga1 = tid + 512;
    const int ar0 = ga0 >> 4,   ax0 = (ga0 & 15) ^ (ar0 & 7);
    const int ar1 = ga1 >> 4,   ax1 = (ga1 & 15) ^ (ar1 & 7);
    const float* asrc0 = adj + (rowbase + ar0) * KDIM + kbase + ax0 * 4;
    const float* asrc1 = adj + (rowbase + ar1) * KDIM + kbase + ax1 * 4;
    const int bn0 = ga0 >> 3,   bx0 = (ga0 & 7) ^ (bn0 & 7);
    const int bn1 = ga1 >> 3,   bx1 = (ga1 & 7) ^ (bn1 & 7);
    const u16* bsrc0 = Bt + (size_t)bn0 * KDIM + kbase + bx0 * 8;
    const u16* bsrc1 = Bt + (size_t)bn1 * KDIM + kbase + bx1 * 8;

    // --- compute indices
    const int lane = tid & 63;
    const int w    = tid >> 6;      // 8 waves
    const int wm   = w >> 1;        // 0..3 : row tile
    const int wn   = w & 1;         // 0..1 : col half
    const int l15  = lane & 15, lg = lane >> 4;
    const int arow = wm * 16 + l15;
    const int asw  = arow & 7;

    f32x4 acc[4];
#pragma unroll
    for (int j = 0; j < 4; ++j) acc[j] = (f32x4){0.f, 0.f, 0.f, 0.f};

    auto stage = [&](int kt, int buf) {
        const int koff = kt * BK;
        char* ab = (char*)Ash[buf];
        char* bb = (char*)Bsh[buf];
        glds16(asrc0 + koff, ab + ga0 * 16);
        glds16(asrc1 + koff, ab + ga1 * 16);
        glds16(bsrc0 + koff, bb + ga0 * 16);
        glds16(bsrc1 + koff, bb + ga1 * 16);
    };

    stage(0, 0);

    for (int t = 0; t < NTI; ++t) {
        __syncthreads();   // compiler drains vmcnt(0): tile t is in LDS
        if (t + 1 < NTI) stage(t + 1, (t + 1) & 1);
        const float4* As4 = (const float4*)Ash[t & 1];
        const short8* Bs8 = (const short8*)Bsh[t & 1];
#pragma unroll
        for (int ks = 0; ks < 2; ++ks) {
            const int x0 = ks * 8 + lg * 2;
            float4 fa = As4[arow * 16 + ((x0    ) ^ asw)];
            float4 fb = As4[arow * 16 + ((x0 + 1) ^ asw)];
            short8 a = cvt8(fa, fb);
            const int bx = ks * 4 + lg;
#pragma unroll
            for (int j = 0; j < 4; ++j) {
                const int n = wn * 32 + (j & 1) * 16 + (j >> 1) * 64 + l15;
                short8 b = Bs8[n * 8 + (bx ^ (n & 7))];
                acc[j] = __builtin_amdgcn_mfma_f32_16x16x32_bf16(a, b, acc[j], 0, 0, 0);
            }
        }
    }

    // partial store: [block][64 rows][128 cols]; C: col=lane&15, row=lg*4+q
    float* pb = Pp + (size_t)blockIdx.x * (BM * BN);
#pragma unroll
    for (int j = 0; j < 2; ++j) {
#pragma unroll
        for (int q = 0; q < 4; ++q) {
            int r = wm * 16 + lg * 4 + q;
            int c = wn * 32 + j * 16 + l15;
            pb[r * BN + c]      = acc[j][q];       // top
            pb[r * BN + c + 64] = acc[j + 2][q];   // down
        }
    }
}

// ---------------- Stage 5: combine K-halves, ratio + mu + bias ------------
__global__ __launch_bounds__(256) void reduce_kernel(
    const float* __restrict__ Pp, const float* __restrict__ bias,
    const float* __restrict__ muptr, float* __restrict__ out)
{
    int idx = blockIdx.x * 256 + threadIdx.x;   // 1M outputs
    int r = idx >> 6, c = idx & 63;
    int rb = r >> 6, rr = r & 63;
    const float* p0 = Pp + (size_t)(rb * 2) * (BM * BN) + rr * BN + c;
    const float* p1 = p0 + BM * BN;
    float T = p0[0]  + p1[0];
    float D = p0[64] + p1[64];
    out[idx] = T / D + muptr[0] + bias[c];
}

extern "C" void kernel_launch(void* const* d_in, const int* in_sizes, int n_in,
                              void* d_out, int out_size, void* d_ws, size_t ws_size,
                              hipStream_t stream)
{
    const float* inp  = (const float*)d_in[0];
    const float* adj  = (const float*)d_in[1];
    const float* W    = (const float*)d_in[2];
    const float* bias = (const float*)d_in[3];
    const int*   p    = (const int*)d_in[4];
    float* out = (float*)d_out;

    // ws layout: Bt 4MB | partmin 1KB | mu | Wt 64KB | (8MB:) Pp 16MB
    char* ws = (char*)d_ws;
    u16*   Bt      = (u16*)ws;
    float* partmin = (float*)(ws + (size_t)4 * 1024 * 1024);
    float* mu      = partmin + 256;
    float* Wt      = (float*)(ws + (size_t)4 * 1024 * 1024 + 4096);
    float* Pp      = (float*)(ws + (size_t)8 * 1024 * 1024);

    float* sup = out;   // park support in d_out; reduce overwrites at the end

    wt_kernel       <<<64,   256, 0, stream>>>(W, Wt);
    support_kernel  <<<512,  256, 0, stream>>>(inp, Wt, sup);
    min_part_kernel <<<256,  256, 0, stream>>>(sup, partmin);
    min_final_kernel<<<1,    256, 0, stream>>>(partmin, mu);
    build_bt_kernel <<<64,   256, 0, stream>>>(sup, mu, p, Bt);
    gemm_kernel     <<<512,  512, 0, stream>>>(adj, Bt, Pp);
    reduce_kernel   <<<4096, 256, 0, stream>>>(Pp, bias, mu, out);
}